// Round 6
// baseline (778.219 us; speedup 1.0000x reference)
//
#include <hip/hip_runtime.h>
#include <cstddef>
#include <cstdint>

#define NE 2048
#define NX 3
#define NROWS (NE - 1)               // rows solved by back-substitution: i = 0..2046
#define BS 64                        // block size (rows per block)
#define BR (3 * BS)                  // 192
#define NBLK 32
#define NCH 8                        // K-staging chunks in k_tinv
#define CHS 8                        // steps per chunk (NCH*CHS == BS)
#define CHQ (CHS * 9 * BS)           // 4608 floats per chunk
#define PERTH (CHQ / 256)            // 18 floats per thread
#define GCH 8                        // far-GEMV chunks per stage (512 WGs)

// ws layout (floats):
//   wf  [3*NE]        @ 0          wf[p][j] = w_j * F[p][j]
//   acc [3*NE]        @ 3*NE       running RHS accumulator
//   Gt  [NBLK*BR*BR]  @ 6*NE       per-block T^{-1}, transposed: Gt[b][col][row]
//   cnt [NBLK] ints   @ end        per-stage ticket counters (zeroed by k_init)

static __device__ __forceinline__ float dy_of(const float* E) {
    return logf(E[NE - 1] / E[0]) / (float)(NE - 1);
}

__global__ void k_init(const float* __restrict__ E, const float* __restrict__ R,
                       const float* __restrict__ K, const float* __restrict__ S0,
                       const float* __restrict__ SC,
                       float* __restrict__ out, float* __restrict__ wf,
                       float* __restrict__ acc, int* __restrict__ cnt) {
    int i = blockIdx.x * blockDim.x + threadIdx.x;
    if (blockIdx.x == 0 && threadIdx.x < NBLK) cnt[threadIdx.x] = 0;
    if (i >= NE) return;
    const size_t PL = (size_t)NE * NE;
    float dy = dy_of(E);
    float wlast = 0.5f * dy * E[NE - 1];
    float srcl[NX], Fl[NX];
#pragma unroll
    for (int p = 0; p < NX; ++p) srcl[p] = S0[p] / R[p * NE + NE - 1];
#pragma unroll
    for (int x = 0; x < NX; ++x) {
        float s = SC[x * NE + NE - 1];
#pragma unroll
        for (int p = 0; p < NX; ++p)
            s += K[(size_t)(x * NX + p) * PL + (size_t)(NE - 1) * NE + (NE - 1)] * srcl[p];
        Fl[x] = s / R[x * NE + NE - 1];
    }
    out[i] = E[i];  // output row 0 = E_grid
    if (i == NE - 1) {
#pragma unroll
        for (int x = 0; x < NX; ++x) {
            out[(1 + x) * NE + i] = Fl[x] > 0.f ? Fl[x] : 0.f;
            wf[x * NE + i] = wlast * Fl[x];
            acc[x * NE + i] = 0.f;
        }
        return;
    }
#pragma unroll
    for (int x = 0; x < NX; ++x) {
        float s = SC[x * NE + i];
#pragma unroll
        for (int p = 0; p < NX; ++p)
            s += K[(size_t)(x * NX + p) * PL + (size_t)i * NE + (NE - 1)] *
                 (wlast * Fl[p] + srcl[p]);
        acc[x * NE + i] = s;
    }
}

// Per-block inverse. grid (NBLK, 3), 64 columns per WG, 4 threads per column.
// Kst packed [s][jj][12] with w folded (3x ds_read_b128 broadcast per iter);
// Xs column-private, same-wave 4-lane groups (wave_barrier ordering only).
__global__ __launch_bounds__(256) void k_tinv(const float* __restrict__ E,
                                              const float* __restrict__ R,
                                              const float* __restrict__ K,
                                              float* __restrict__ Gt) {
    __shared__ float Xs[BR][BS];        // 49152 B: Xs[row][local col]
    __shared__ float Kst[CHS][BS][12];  // 24576 B: w-folded K rows, slot 4r+p
    __shared__ float Binv[BS][9];
    __shared__ float wloc[BS];
    const size_t PL = (size_t)NE * NE;
    int b = blockIdx.x;
    int g = blockIdx.y;                 // column group 0..2
    int i0 = b * BS;
    int tid = threadIdx.x;
    float dy = dy_of(E);

    if (tid < BS) {
        int j = i0 + tid;
        wloc[tid] = (j < NE - 1) ? dy * E[j] : 0.f;
        int ii = tid, i = i0 + ii;
        float b00, b01, b02, b10, b11, b12, b20, b21, b22;
        if (i < NROWS) {
            float h = -0.5f * dy * E[i];
            size_t d = (size_t)i * NE + i;
            b00 = h * K[0 * PL + d] + R[0 * NE + i];
            b01 = h * K[1 * PL + d];
            b02 = h * K[2 * PL + d];
            b10 = h * K[3 * PL + d];
            b11 = h * K[4 * PL + d] + R[1 * NE + i];
            b12 = h * K[5 * PL + d];
            b20 = h * K[6 * PL + d];
            b21 = h * K[7 * PL + d];
            b22 = h * K[8 * PL + d] + R[2 * NE + i];
        } else {
            b00 = 1.f; b01 = 0.f; b02 = 0.f;
            b10 = 0.f; b11 = 1.f; b12 = 0.f;
            b20 = 0.f; b21 = 0.f; b22 = 1.f;
        }
        float C00 = b11 * b22 - b12 * b21;
        float C01 = -(b10 * b22 - b12 * b20);
        float C02 = b10 * b21 - b11 * b20;
        float C10 = -(b01 * b22 - b02 * b21);
        float C11 = b00 * b22 - b02 * b20;
        float C12 = -(b00 * b21 - b01 * b20);
        float C20 = b01 * b12 - b02 * b11;
        float C21 = -(b00 * b12 - b02 * b10);
        float C22 = b00 * b11 - b01 * b10;
        float inv = 1.f / (b00 * C00 + b01 * C01 + b02 * C02);
        Binv[ii][0] = C00 * inv; Binv[ii][1] = C10 * inv; Binv[ii][2] = C20 * inv;
        Binv[ii][3] = C01 * inv; Binv[ii][4] = C11 * inv; Binv[ii][5] = C21 * inv;
        Binv[ii][6] = C02 * inv; Binv[ii][7] = C12 * inv; Binv[ii][8] = C22 * inv;
    }
    __syncthreads();

    float rg[PERTH];
#pragma unroll
    for (int k = 0; k < PERTH; ++k) {
        int q = tid + k * 256;
        int s = q / (9 * BS);
        int pair = (q / BS) % 9;
        int jj = q & (BS - 1);
        int row = i0 + (BS - 1) - s;
        rg[k] = K[(size_t)pair * PL + (size_t)row * NE + (i0 + jj)];
    }

    int cloc = tid >> 2, sub = tid & 3;
    int colb = g * BS + cloc;

    for (int c = 0; c < NCH; ++c) {
        if (c > 0) __syncthreads();
#pragma unroll
        for (int k = 0; k < PERTH; ++k) {
            int q = tid + k * 256;
            int s = q / (9 * BS);
            int pair = (q / BS) % 9;
            int jj = q & (BS - 1);
            Kst[s][jj][4 * (pair / 3) + (pair % 3)] = rg[k] * wloc[jj];
        }
        __syncthreads();
        if (c + 1 < NCH) {
#pragma unroll
            for (int k = 0; k < PERTH; ++k) {
                int q = tid + k * 256;
                int s = q / (9 * BS);
                int pair = (q / BS) % 9;
                int jj = q & (BS - 1);
                int row = i0 + (BS - 1) - ((c + 1) * CHS + s);
                rg[k] = K[(size_t)pair * PL + (size_t)row * NE + (i0 + jj)];
            }
        }
        for (int s = 0; s < CHS; ++s) {
            int ii = (BS - 1) - (c * CHS + s);
            int i = i0 + ii;
            float v0 = 0.f, v1 = 0.f, v2 = 0.f;
            if (sub == 0) {
                v0 = (colb == 3 * ii + 0) ? 1.f : 0.f;
                v1 = (colb == 3 * ii + 1) ? 1.f : 0.f;
                v2 = (colb == 3 * ii + 2) ? 1.f : 0.f;
            }
            if (i < NROWS) {
                for (int jj = ii + 1 + sub; jj < BS; jj += 4) {
                    const float* kp = &Kst[s][jj][0];
                    float4 k0 = *(const float4*)(kp);
                    float4 k1 = *(const float4*)(kp + 4);
                    float4 k2 = *(const float4*)(kp + 8);
                    float x0 = Xs[3 * jj + 0][cloc];
                    float x1 = Xs[3 * jj + 1][cloc];
                    float x2 = Xs[3 * jj + 2][cloc];
                    v0 += k0.x * x0 + k0.y * x1 + k0.z * x2;
                    v1 += k1.x * x0 + k1.y * x1 + k1.z * x2;
                    v2 += k2.x * x0 + k2.y * x1 + k2.z * x2;
                }
            }
            v0 += __shfl_xor(v0, 1); v0 += __shfl_xor(v0, 2);
            v1 += __shfl_xor(v1, 1); v1 += __shfl_xor(v1, 2);
            v2 += __shfl_xor(v2, 1); v2 += __shfl_xor(v2, 2);
            if (sub == 0) {
                float f0, f1, f2;
                if (i < NROWS) {
                    const float* bv = Binv[ii];
                    f0 = bv[0] * v0 + bv[1] * v1 + bv[2] * v2;
                    f1 = bv[3] * v0 + bv[4] * v1 + bv[5] * v2;
                    f2 = bv[6] * v0 + bv[7] * v1 + bv[8] * v2;
                } else {
                    f0 = v0; f1 = v1; f2 = v2;  // identity row (pad)
                }
                Xs[3 * ii + 0][cloc] = f0;
                Xs[3 * ii + 1][cloc] = f1;
                Xs[3 * ii + 2][cloc] = f2;
            }
            __builtin_amdgcn_wave_barrier();  // order LDS write->read across steps
        }
    }
    __syncthreads();
    // bulk coalesced Gt dump: Gt[b][g*64+cl][ro]
    float* Gb = Gt + (size_t)b * BR * BR + (size_t)g * BS * BR;
    for (int t = tid; t < BS * BR; t += 256) {
        int cl = t / BR, ro = t % BR;
        Gb[t] = Xs[ro][cl];
    }
}

// Fused stage: far-panel gemv WGs + "last ticket does the apply" epilogue.
// Ticket is RELAXED: each WG's __syncthreads() already drains vmcnt(0) after
// its acc-RMWs, so ticket order == acc-visibility order; no L2 wb/inv needed.
__global__ __launch_bounds__(256) void k_stage(const float* __restrict__ E,
                                               const float* __restrict__ K,
                                               const float* __restrict__ Gt,
                                               float* __restrict__ acc,
                                               float* __restrict__ wf,
                                               float* __restrict__ out,
                                               int* __restrict__ cnt,
                                               int b, int nGemv, int chunks) {
    const size_t PL = (size_t)NE * NE;
    int i0 = b * BS;
    int tid = threadIdx.x;
    int bid = blockIdx.x;
    __shared__ int win;

    if (nGemv > 0) {
        int rowIdx = bid & (BS - 1);
        int ck = bid >> 6;
        int i = i0 + rowIdx;
        int jlo = i0 + BS, jhi = NROWS;
        int len = jhi - jlo;
        int per = (len + chunks - 1) / chunks;
        int lo = jlo + ck * per;
        int hi = min(lo + per, jhi);
        float s0 = 0.f, s1 = 0.f, s2 = 0.f;
        if (i < NROWS) {
            for (int j = lo + tid; j < hi; j += 256) {
                float w0 = wf[0 * NE + j], w1 = wf[1 * NE + j], w2 = wf[2 * NE + j];
                const float* Kb = K + (size_t)i * NE + j;
                s0 += Kb[0 * PL] * w0 + Kb[1 * PL] * w1 + Kb[2 * PL] * w2;
                s1 += Kb[3 * PL] * w0 + Kb[4 * PL] * w1 + Kb[5 * PL] * w2;
                s2 += Kb[6 * PL] * w0 + Kb[7 * PL] * w1 + Kb[8 * PL] * w2;
            }
        }
#pragma unroll
        for (int m = 32; m; m >>= 1) {
            s0 += __shfl_xor(s0, m);
            s1 += __shfl_xor(s1, m);
            s2 += __shfl_xor(s2, m);
        }
        __shared__ float red[4][3];
        int wv = tid >> 6;
        if ((tid & 63) == 0) { red[wv][0] = s0; red[wv][1] = s1; red[wv][2] = s2; }
        __syncthreads();
        if (tid == 0 && i < NROWS) {
            atomicAdd(&acc[0 * NE + i], red[0][0] + red[1][0] + red[2][0] + red[3][0]);
            atomicAdd(&acc[1 * NE + i], red[0][1] + red[1][1] + red[2][1] + red[3][1]);
            atomicAdd(&acc[2 * NE + i], red[0][2] + red[1][2] + red[2][2] + red[3][2]);
        }
        // barrier drains vmcnt(0) -> this WG's RMWs are globally performed
        __syncthreads();
        if (tid == 0) {
            int ret = __hip_atomic_fetch_add(&cnt[b], 1, __ATOMIC_RELAXED,
                                             __HIP_MEMORY_SCOPE_AGENT);
            win = (ret == nGemv - 1) ? 1 : 0;
        }
        __syncthreads();
        if (!win) return;
        __syncthreads();  // re-converge before the apply's shared-mem phase
    }

    // Apply: F_blk = Gt[b] @ acc_blk (winner WG only, or the sole WG if nGemv==0)
    __shared__ float aL[BR];
    if (tid < BR) {
        int jj = tid / 3, p = tid % 3;
        int j = i0 + jj;
        aL[tid] = (j < NROWS)
            ? __hip_atomic_load(&acc[p * NE + j], __ATOMIC_RELAXED, __HIP_MEMORY_SCOPE_AGENT)
            : 0.f;
    }
    __syncthreads();
    if (tid < BR) {
        const float* gcol = Gt + (size_t)b * BR * BR;  // Gt[c][r] = gcol[c*BR+r]
        float s = 0.f;
#pragma unroll 4
        for (int cc = 0; cc < BR; ++cc)
            s += gcol[(size_t)cc * BR + tid] * aL[cc];
        int ii = tid / 3, x = tid % 3;
        int i = i0 + ii;
        if (i < NROWS) {
            float dy = dy_of(E);
            out[(1 + x) * NE + i] = s > 0.f ? s : 0.f;
            wf[x * NE + i] = dy * E[i] * s;
        }
    }
}

extern "C" void kernel_launch(void* const* d_in, const int* in_sizes, int n_in,
                              void* d_out, int out_size, void* d_ws, size_t ws_size,
                              hipStream_t stream) {
    const float* E = (const float*)d_in[0];
    const float* R = (const float*)d_in[1];
    const float* K = (const float*)d_in[2];
    const float* S0 = (const float*)d_in[3];
    const float* SC = (const float*)d_in[4];
    float* out = (float*)d_out;
    float* wf = (float*)d_ws;
    float* acc = wf + NX * NE;
    float* Gt = acc + NX * NE;
    int* cnt = (int*)(Gt + (size_t)NBLK * BR * BR);

    k_init<<<(NE + 255) / 256, 256, 0, stream>>>(E, R, K, S0, SC, out, wf, acc, cnt);
    k_tinv<<<dim3(NBLK, 3), 256, 0, stream>>>(E, R, K, Gt);

    for (int b = NBLK - 1; b >= 0; --b) {
        int i0 = b * BS;
        int len = NROWS - (i0 + BS);
        int chunks = 0, nGemv = 0;
        if (len > 0) {
            chunks = GCH;               // fixed 512 WGs/stage: keep CUs busy
            nGemv = chunks * BS;
        }
        k_stage<<<(nGemv > 0 ? nGemv : 1), 256, 0, stream>>>(E, K, Gt, acc, wf, out,
                                                             cnt, b, nGemv, chunks);
    }
}

// Round 7
// 574.452 us; speedup vs baseline: 1.3547x; 1.3547x over previous
//
#include <hip/hip_runtime.h>
#include <cstddef>
#include <cstdint>

#define NE 2048
#define NX 3
#define NROWS (NE - 1)               // rows solved by back-substitution: i = 0..2046
#define BS 64                        // block size (rows per block)
#define BR (3 * BS)                  // 192
#define NBLK 32
#define NCH 8                        // K-staging chunks in k_tinv
#define CHS 8                        // steps per chunk (NCH*CHS == BS)
#define CHQ (CHS * 9 * BS)           // 4608 floats per chunk
#define PERTH (CHQ / 256)            // 18 floats per thread
#define GCH 8                        // far-GEMV chunks per stage (512 WGs)

// ws layout (floats):
//   wf  [3*NE]        @ 0          wf[p][j] = w_j * F[p][j]
//   acc [3*NE]        @ 3*NE       running RHS accumulator
//   G   [NBLK*BR*BR]  @ 6*NE       per-block T^{-1}, ROW-major: G[b][row][col]
//   cnt [NBLK] ints   @ end        per-stage ticket counters (zeroed by k_init)

static __device__ __forceinline__ float dy_of(const float* E) {
    return logf(E[NE - 1] / E[0]) / (float)(NE - 1);
}

__global__ void k_init(const float* __restrict__ E, const float* __restrict__ R,
                       const float* __restrict__ K, const float* __restrict__ S0,
                       const float* __restrict__ SC,
                       float* __restrict__ out, float* __restrict__ wf,
                       float* __restrict__ acc, int* __restrict__ cnt) {
    int i = blockIdx.x * blockDim.x + threadIdx.x;
    if (blockIdx.x == 0 && threadIdx.x < NBLK) cnt[threadIdx.x] = 0;
    if (i >= NE) return;
    const size_t PL = (size_t)NE * NE;
    float dy = dy_of(E);
    float wlast = 0.5f * dy * E[NE - 1];
    float srcl[NX], Fl[NX];
#pragma unroll
    for (int p = 0; p < NX; ++p) srcl[p] = S0[p] / R[p * NE + NE - 1];
#pragma unroll
    for (int x = 0; x < NX; ++x) {
        float s = SC[x * NE + NE - 1];
#pragma unroll
        for (int p = 0; p < NX; ++p)
            s += K[(size_t)(x * NX + p) * PL + (size_t)(NE - 1) * NE + (NE - 1)] * srcl[p];
        Fl[x] = s / R[x * NE + NE - 1];
    }
    out[i] = E[i];  // output row 0 = E_grid
    if (i == NE - 1) {
#pragma unroll
        for (int x = 0; x < NX; ++x) {
            out[(1 + x) * NE + i] = Fl[x] > 0.f ? Fl[x] : 0.f;
            wf[x * NE + i] = wlast * Fl[x];
            acc[x * NE + i] = 0.f;
        }
        return;
    }
#pragma unroll
    for (int x = 0; x < NX; ++x) {
        float s = SC[x * NE + i];
#pragma unroll
        for (int p = 0; p < NX; ++p)
            s += K[(size_t)(x * NX + p) * PL + (size_t)i * NE + (NE - 1)] *
                 (wlast * Fl[p] + srcl[p]);
        acc[x * NE + i] = s;
    }
}

// Per-block inverse. grid (NBLK, 3), 64 columns per WG, 4 threads per column.
// X stored as padded float4 [64][65] -> 1 ds_read_b128 per (jj) with even bank
// spread; Kst packed [s][jj][12] w-folded (3x b128 broadcast).
__global__ __launch_bounds__(256) void k_tinv(const float* __restrict__ E,
                                              const float* __restrict__ R,
                                              const float* __restrict__ K,
                                              float* __restrict__ G) {
    __shared__ float4 Xs4[BS][BS + 1];  // 66560 B: [jj][cloc] = (x0,x1,x2,_)
    __shared__ float Kst[CHS][BS][12];  // 24576 B: w-folded K rows, slot 4r+p
    __shared__ float Binv[BS][9];
    __shared__ float wloc[BS];
    const size_t PL = (size_t)NE * NE;
    int b = blockIdx.x;
    int g = blockIdx.y;                 // column group 0..2
    int i0 = b * BS;
    int tid = threadIdx.x;
    float dy = dy_of(E);

    if (tid < BS) {
        int j = i0 + tid;
        wloc[tid] = (j < NE - 1) ? dy * E[j] : 0.f;
        int ii = tid, i = i0 + ii;
        float b00, b01, b02, b10, b11, b12, b20, b21, b22;
        if (i < NROWS) {
            float h = -0.5f * dy * E[i];
            size_t d = (size_t)i * NE + i;
            b00 = h * K[0 * PL + d] + R[0 * NE + i];
            b01 = h * K[1 * PL + d];
            b02 = h * K[2 * PL + d];
            b10 = h * K[3 * PL + d];
            b11 = h * K[4 * PL + d] + R[1 * NE + i];
            b12 = h * K[5 * PL + d];
            b20 = h * K[6 * PL + d];
            b21 = h * K[7 * PL + d];
            b22 = h * K[8 * PL + d] + R[2 * NE + i];
        } else {
            b00 = 1.f; b01 = 0.f; b02 = 0.f;
            b10 = 0.f; b11 = 1.f; b12 = 0.f;
            b20 = 0.f; b21 = 0.f; b22 = 1.f;
        }
        float C00 = b11 * b22 - b12 * b21;
        float C01 = -(b10 * b22 - b12 * b20);
        float C02 = b10 * b21 - b11 * b20;
        float C10 = -(b01 * b22 - b02 * b21);
        float C11 = b00 * b22 - b02 * b20;
        float C12 = -(b00 * b21 - b01 * b20);
        float C20 = b01 * b12 - b02 * b11;
        float C21 = -(b00 * b12 - b02 * b10);
        float C22 = b00 * b11 - b01 * b10;
        float inv = 1.f / (b00 * C00 + b01 * C01 + b02 * C02);
        Binv[ii][0] = C00 * inv; Binv[ii][1] = C10 * inv; Binv[ii][2] = C20 * inv;
        Binv[ii][3] = C01 * inv; Binv[ii][4] = C11 * inv; Binv[ii][5] = C21 * inv;
        Binv[ii][6] = C02 * inv; Binv[ii][7] = C12 * inv; Binv[ii][8] = C22 * inv;
    }
    __syncthreads();

    float rg[PERTH];
#pragma unroll
    for (int k = 0; k < PERTH; ++k) {
        int q = tid + k * 256;
        int s = q / (9 * BS);
        int pair = (q / BS) % 9;
        int jj = q & (BS - 1);
        int row = i0 + (BS - 1) - s;
        rg[k] = K[(size_t)pair * PL + (size_t)row * NE + (i0 + jj)];
    }

    int cloc = tid >> 2, sub = tid & 3;
    int colb = g * BS + cloc;

    for (int c = 0; c < NCH; ++c) {
        if (c > 0) __syncthreads();
#pragma unroll
        for (int k = 0; k < PERTH; ++k) {
            int q = tid + k * 256;
            int s = q / (9 * BS);
            int pair = (q / BS) % 9;
            int jj = q & (BS - 1);
            Kst[s][jj][4 * (pair / 3) + (pair % 3)] = rg[k] * wloc[jj];
        }
        __syncthreads();
        if (c + 1 < NCH) {
#pragma unroll
            for (int k = 0; k < PERTH; ++k) {
                int q = tid + k * 256;
                int s = q / (9 * BS);
                int pair = (q / BS) % 9;
                int jj = q & (BS - 1);
                int row = i0 + (BS - 1) - ((c + 1) * CHS + s);
                rg[k] = K[(size_t)pair * PL + (size_t)row * NE + (i0 + jj)];
            }
        }
        for (int s = 0; s < CHS; ++s) {
            int ii = (BS - 1) - (c * CHS + s);
            int i = i0 + ii;
            float v0 = 0.f, v1 = 0.f, v2 = 0.f;
            if (sub == 0) {
                v0 = (colb == 3 * ii + 0) ? 1.f : 0.f;
                v1 = (colb == 3 * ii + 1) ? 1.f : 0.f;
                v2 = (colb == 3 * ii + 2) ? 1.f : 0.f;
            }
            if (i < NROWS) {
                for (int jj = ii + 1 + sub; jj < BS; jj += 4) {
                    const float* kp = &Kst[s][jj][0];
                    float4 k0 = *(const float4*)(kp);
                    float4 k1 = *(const float4*)(kp + 4);
                    float4 k2 = *(const float4*)(kp + 8);
                    float4 xv = Xs4[jj][cloc];
                    v0 += k0.x * xv.x + k0.y * xv.y + k0.z * xv.z;
                    v1 += k1.x * xv.x + k1.y * xv.y + k1.z * xv.z;
                    v2 += k2.x * xv.x + k2.y * xv.y + k2.z * xv.z;
                }
            }
            v0 += __shfl_xor(v0, 1); v0 += __shfl_xor(v0, 2);
            v1 += __shfl_xor(v1, 1); v1 += __shfl_xor(v1, 2);
            v2 += __shfl_xor(v2, 1); v2 += __shfl_xor(v2, 2);
            if (sub == 0) {
                float f0, f1, f2;
                if (i < NROWS) {
                    const float* bv = Binv[ii];
                    f0 = bv[0] * v0 + bv[1] * v1 + bv[2] * v2;
                    f1 = bv[3] * v0 + bv[4] * v1 + bv[5] * v2;
                    f2 = bv[6] * v0 + bv[7] * v1 + bv[8] * v2;
                } else {
                    f0 = v0; f1 = v1; f2 = v2;  // identity row (pad)
                }
                Xs4[ii][cloc] = make_float4(f0, f1, f2, 0.f);
            }
            __builtin_amdgcn_wave_barrier();  // order LDS write->read across steps
        }
    }
    __syncthreads();
    // bulk Gt dump, ROW-major: G[b][r][g*64+cl]
    float* Gb = G + (size_t)b * BR * BR;
    for (int t = tid; t < BS * BR; t += 256) {
        int r = t / BS, cl = t % BS;
        Gb[(size_t)r * BR + g * BS + cl] = ((const float*)&Xs4[r / 3][cl])[r % 3];
    }
}

// Fused stage: far-panel gemv WGs + "last ticket does the apply" epilogue.
// Ticket RELAXED (each WG's __syncthreads drains vmcnt(0) after its acc-RMWs).
__global__ __launch_bounds__(256) void k_stage(const float* __restrict__ E,
                                               const float* __restrict__ K,
                                               const float* __restrict__ G,
                                               float* __restrict__ acc,
                                               float* __restrict__ wf,
                                               float* __restrict__ out,
                                               int* __restrict__ cnt,
                                               int b, int nGemv, int chunks) {
    const size_t PL = (size_t)NE * NE;
    int i0 = b * BS;
    int tid = threadIdx.x;
    int bid = blockIdx.x;
    __shared__ int win;

    if (nGemv > 0) {
        int rowIdx = bid & (BS - 1);
        int ck = bid >> 6;
        int i = i0 + rowIdx;
        int jlo = i0 + BS, jhi = NROWS;
        int len = jhi - jlo;
        int per = (len + chunks - 1) / chunks;
        int lo = jlo + ck * per;
        int hi = min(lo + per, jhi);
        float s0 = 0.f, s1 = 0.f, s2 = 0.f;
        if (i < NROWS) {
            for (int j = lo + tid; j < hi; j += 256) {
                float w0 = wf[0 * NE + j], w1 = wf[1 * NE + j], w2 = wf[2 * NE + j];
                const float* Kb = K + (size_t)i * NE + j;
                s0 += Kb[0 * PL] * w0 + Kb[1 * PL] * w1 + Kb[2 * PL] * w2;
                s1 += Kb[3 * PL] * w0 + Kb[4 * PL] * w1 + Kb[5 * PL] * w2;
                s2 += Kb[6 * PL] * w0 + Kb[7 * PL] * w1 + Kb[8 * PL] * w2;
            }
        }
#pragma unroll
        for (int m = 32; m; m >>= 1) {
            s0 += __shfl_xor(s0, m);
            s1 += __shfl_xor(s1, m);
            s2 += __shfl_xor(s2, m);
        }
        __shared__ float red[4][3];
        int wv = tid >> 6;
        if ((tid & 63) == 0) { red[wv][0] = s0; red[wv][1] = s1; red[wv][2] = s2; }
        __syncthreads();
        if (tid == 0 && i < NROWS) {
            atomicAdd(&acc[0 * NE + i], red[0][0] + red[1][0] + red[2][0] + red[3][0]);
            atomicAdd(&acc[1 * NE + i], red[0][1] + red[1][1] + red[2][1] + red[3][1]);
            atomicAdd(&acc[2 * NE + i], red[0][2] + red[1][2] + red[2][2] + red[3][2]);
        }
        // barrier drains vmcnt(0) -> this WG's RMWs are globally performed
        __syncthreads();
        if (tid == 0) {
            int ret = __hip_atomic_fetch_add(&cnt[b], 1, __ATOMIC_RELAXED,
                                             __HIP_MEMORY_SCOPE_AGENT);
            win = (ret == nGemv - 1) ? 1 : 0;
        }
        __syncthreads();
        if (!win) return;
        __syncthreads();  // re-converge before the apply's shared-mem phase
    }

    // Apply: F_blk = G[b] @ acc_blk. 192 threads, 48 fully-unrolled float4/row.
    __shared__ float4 aL4[BR / 4];
    if (tid < BR) {
        int jj = tid / 3, p = tid % 3;
        int j = i0 + jj;
        ((float*)aL4)[tid] = (j < NROWS)
            ? __hip_atomic_load(&acc[p * NE + j], __ATOMIC_RELAXED, __HIP_MEMORY_SCOPE_AGENT)
            : 0.f;
    }
    __syncthreads();
    if (tid < BR) {
        const float4* row = (const float4*)(G + ((size_t)b * BR + tid) * BR);
        float s0 = 0.f, s1 = 0.f;
#pragma unroll
        for (int c = 0; c < BR / 4; c += 2) {
            float4 g0 = row[c], g1 = row[c + 1];
            float4 a0 = aL4[c], a1 = aL4[c + 1];
            s0 += g0.x * a0.x + g0.y * a0.y + g0.z * a0.z + g0.w * a0.w;
            s1 += g1.x * a1.x + g1.y * a1.y + g1.z * a1.z + g1.w * a1.w;
        }
        float s = s0 + s1;
        int ii = tid / 3, x = tid % 3;
        int i = i0 + ii;
        if (i < NROWS) {
            float dy = dy_of(E);
            out[(1 + x) * NE + i] = s > 0.f ? s : 0.f;
            wf[x * NE + i] = dy * E[i] * s;
        }
    }
}

extern "C" void kernel_launch(void* const* d_in, const int* in_sizes, int n_in,
                              void* d_out, int out_size, void* d_ws, size_t ws_size,
                              hipStream_t stream) {
    const float* E = (const float*)d_in[0];
    const float* R = (const float*)d_in[1];
    const float* K = (const float*)d_in[2];
    const float* S0 = (const float*)d_in[3];
    const float* SC = (const float*)d_in[4];
    float* out = (float*)d_out;
    float* wf = (float*)d_ws;
    float* acc = wf + NX * NE;
    float* G = acc + NX * NE;
    int* cnt = (int*)(G + (size_t)NBLK * BR * BR);

    k_init<<<(NE + 255) / 256, 256, 0, stream>>>(E, R, K, S0, SC, out, wf, acc, cnt);
    k_tinv<<<dim3(NBLK, 3), 256, 0, stream>>>(E, R, K, G);

    for (int b = NBLK - 1; b >= 0; --b) {
        int i0 = b * BS;
        int len = NROWS - (i0 + BS);
        int chunks = 0, nGemv = 0;
        if (len > 0) {
            chunks = GCH;               // fixed 512 WGs/stage: keep CUs busy
            nGemv = chunks * BS;
        }
        k_stage<<<(nGemv > 0 ? nGemv : 1), 256, 0, stream>>>(E, K, G, acc, wf, out,
                                                             cnt, b, nGemv, chunks);
    }
}

// Round 8
// 379.034 us; speedup vs baseline: 2.0532x; 1.5156x over previous
//
#include <hip/hip_runtime.h>
#include <cstddef>
#include <cstdint>

#define NE 2048
#define NX 3
#define NROWS (NE - 1)               // rows solved by back-substitution: i = 0..2046
#define BS 64                        // block size (rows per block)
#define BR (3 * BS)                  // 192
#define NBLK 32
#define NCH 8                        // K-staging chunks in k_tinv
#define CHS 8                        // steps per chunk (NCH*CHS == BS)
#define CHQ (CHS * 9 * BS)           // 4608 floats per chunk
#define TTH 512                      // k_tinv threads
#define PERTH (CHQ / TTH)            // 9 floats per thread
#define NNEAR 16                     // near WGs per stage (4 rows each)

// ws layout (floats):
//   wf  [3*NE]        @ 0          wf[p][j] = w_j * F[p][j]
//   acc [3*NE]        @ 3*NE       running RHS accumulator
//   G   [NBLK*BR*BR]  @ 6*NE       per-block T^{-1}, ROW-major: G[b][row][col]
//   cnt [NBLK] ints   @ end        per-stage ticket counters (zeroed by k_init)

static __device__ __forceinline__ float dy_of(const float* E) {
    return logf(E[NE - 1] / E[0]) / (float)(NE - 1);
}

__global__ void k_init(const float* __restrict__ E, const float* __restrict__ R,
                       const float* __restrict__ K, const float* __restrict__ S0,
                       const float* __restrict__ SC,
                       float* __restrict__ out, float* __restrict__ wf,
                       float* __restrict__ acc, int* __restrict__ cnt) {
    int i = blockIdx.x * blockDim.x + threadIdx.x;
    if (blockIdx.x == 0 && threadIdx.x < NBLK) cnt[threadIdx.x] = 0;
    if (i >= NE) return;
    const size_t PL = (size_t)NE * NE;
    float dy = dy_of(E);
    float wlast = 0.5f * dy * E[NE - 1];
    float srcl[NX], Fl[NX];
#pragma unroll
    for (int p = 0; p < NX; ++p) srcl[p] = S0[p] / R[p * NE + NE - 1];
#pragma unroll
    for (int x = 0; x < NX; ++x) {
        float s = SC[x * NE + NE - 1];
#pragma unroll
        for (int p = 0; p < NX; ++p)
            s += K[(size_t)(x * NX + p) * PL + (size_t)(NE - 1) * NE + (NE - 1)] * srcl[p];
        Fl[x] = s / R[x * NE + NE - 1];
    }
    out[i] = E[i];  // output row 0 = E_grid
    if (i == NE - 1) {
#pragma unroll
        for (int x = 0; x < NX; ++x) {
            out[(1 + x) * NE + i] = Fl[x] > 0.f ? Fl[x] : 0.f;
            wf[x * NE + i] = wlast * Fl[x];
            acc[x * NE + i] = 0.f;
        }
        return;
    }
#pragma unroll
    for (int x = 0; x < NX; ++x) {
        float s = SC[x * NE + i];
#pragma unroll
        for (int p = 0; p < NX; ++p)
            s += K[(size_t)(x * NX + p) * PL + (size_t)i * NE + (NE - 1)] *
                 (wlast * Fl[p] + srcl[p]);
        acc[x * NE + i] = s;
    }
}

// Per-block inverse. grid (NBLK, 3), 512 threads: 64 columns/WG, 8 threads/col.
__global__ __launch_bounds__(TTH) void k_tinv(const float* __restrict__ E,
                                              const float* __restrict__ R,
                                              const float* __restrict__ K,
                                              float* __restrict__ G) {
    __shared__ float4 Xs4[BS][BS + 1];  // 66560 B: [jj][cloc] = (x0,x1,x2,_)
    __shared__ float Kst[CHS][BS][12];  // 24576 B: w-folded K rows, slot 4r+p
    __shared__ float Binv[BS][9];
    __shared__ float wloc[BS];
    const size_t PL = (size_t)NE * NE;
    int b = blockIdx.x;
    int g = blockIdx.y;                 // column group 0..2
    int i0 = b * BS;
    int tid = threadIdx.x;
    float dy = dy_of(E);

    if (tid < BS) {
        int j = i0 + tid;
        wloc[tid] = (j < NE - 1) ? dy * E[j] : 0.f;
        int ii = tid, i = i0 + ii;
        float b00, b01, b02, b10, b11, b12, b20, b21, b22;
        if (i < NROWS) {
            float h = -0.5f * dy * E[i];
            size_t d = (size_t)i * NE + i;
            b00 = h * K[0 * PL + d] + R[0 * NE + i];
            b01 = h * K[1 * PL + d];
            b02 = h * K[2 * PL + d];
            b10 = h * K[3 * PL + d];
            b11 = h * K[4 * PL + d] + R[1 * NE + i];
            b12 = h * K[5 * PL + d];
            b20 = h * K[6 * PL + d];
            b21 = h * K[7 * PL + d];
            b22 = h * K[8 * PL + d] + R[2 * NE + i];
        } else {
            b00 = 1.f; b01 = 0.f; b02 = 0.f;
            b10 = 0.f; b11 = 1.f; b12 = 0.f;
            b20 = 0.f; b21 = 0.f; b22 = 1.f;
        }
        float C00 = b11 * b22 - b12 * b21;
        float C01 = -(b10 * b22 - b12 * b20);
        float C02 = b10 * b21 - b11 * b20;
        float C10 = -(b01 * b22 - b02 * b21);
        float C11 = b00 * b22 - b02 * b20;
        float C12 = -(b00 * b21 - b01 * b20);
        float C20 = b01 * b12 - b02 * b11;
        float C21 = -(b00 * b12 - b02 * b10);
        float C22 = b00 * b11 - b01 * b10;
        float inv = 1.f / (b00 * C00 + b01 * C01 + b02 * C02);
        Binv[ii][0] = C00 * inv; Binv[ii][1] = C10 * inv; Binv[ii][2] = C20 * inv;
        Binv[ii][3] = C01 * inv; Binv[ii][4] = C11 * inv; Binv[ii][5] = C21 * inv;
        Binv[ii][6] = C02 * inv; Binv[ii][7] = C12 * inv; Binv[ii][8] = C22 * inv;
    }
    __syncthreads();

    float rg[PERTH];
#pragma unroll
    for (int k = 0; k < PERTH; ++k) {
        int q = tid + k * TTH;
        int s = q / (9 * BS);
        int pair = (q / BS) % 9;
        int jj = q & (BS - 1);
        int row = i0 + (BS - 1) - s;
        rg[k] = K[(size_t)pair * PL + (size_t)row * NE + (i0 + jj)];
    }

    int cloc = tid >> 3, sub = tid & 7;
    int colb = g * BS + cloc;

    for (int c = 0; c < NCH; ++c) {
        if (c > 0) __syncthreads();
#pragma unroll
        for (int k = 0; k < PERTH; ++k) {
            int q = tid + k * TTH;
            int s = q / (9 * BS);
            int pair = (q / BS) % 9;
            int jj = q & (BS - 1);
            Kst[s][jj][4 * (pair / 3) + (pair % 3)] = rg[k] * wloc[jj];
        }
        __syncthreads();
        if (c + 1 < NCH) {
#pragma unroll
            for (int k = 0; k < PERTH; ++k) {
                int q = tid + k * TTH;
                int s = q / (9 * BS);
                int pair = (q / BS) % 9;
                int jj = q & (BS - 1);
                int row = i0 + (BS - 1) - ((c + 1) * CHS + s);
                rg[k] = K[(size_t)pair * PL + (size_t)row * NE + (i0 + jj)];
            }
        }
        for (int s = 0; s < CHS; ++s) {
            int ii = (BS - 1) - (c * CHS + s);
            int i = i0 + ii;
            float v0 = 0.f, v1 = 0.f, v2 = 0.f;
            if (sub == 0) {
                v0 = (colb == 3 * ii + 0) ? 1.f : 0.f;
                v1 = (colb == 3 * ii + 1) ? 1.f : 0.f;
                v2 = (colb == 3 * ii + 2) ? 1.f : 0.f;
            }
            if (i < NROWS) {
                for (int jj = ii + 1 + sub; jj < BS; jj += 8) {
                    const float* kp = &Kst[s][jj][0];
                    float4 k0 = *(const float4*)(kp);
                    float4 k1 = *(const float4*)(kp + 4);
                    float4 k2 = *(const float4*)(kp + 8);
                    float4 xv = Xs4[jj][cloc];
                    v0 += k0.x * xv.x + k0.y * xv.y + k0.z * xv.z;
                    v1 += k1.x * xv.x + k1.y * xv.y + k1.z * xv.z;
                    v2 += k2.x * xv.x + k2.y * xv.y + k2.z * xv.z;
                }
            }
            v0 += __shfl_xor(v0, 1); v0 += __shfl_xor(v0, 2); v0 += __shfl_xor(v0, 4);
            v1 += __shfl_xor(v1, 1); v1 += __shfl_xor(v1, 2); v1 += __shfl_xor(v1, 4);
            v2 += __shfl_xor(v2, 1); v2 += __shfl_xor(v2, 2); v2 += __shfl_xor(v2, 4);
            if (sub == 0) {
                float f0, f1, f2;
                if (i < NROWS) {
                    const float* bv = Binv[ii];
                    f0 = bv[0] * v0 + bv[1] * v1 + bv[2] * v2;
                    f1 = bv[3] * v0 + bv[4] * v1 + bv[5] * v2;
                    f2 = bv[6] * v0 + bv[7] * v1 + bv[8] * v2;
                } else {
                    f0 = v0; f1 = v1; f2 = v2;  // identity row (pad)
                }
                Xs4[ii][cloc] = make_float4(f0, f1, f2, 0.f);
            }
            __builtin_amdgcn_wave_barrier();  // order LDS write->read across steps
        }
    }
    __syncthreads();
    // bulk Gt dump, ROW-major: G[b][r][g*64+cl]
    float* Gb = G + (size_t)b * BR * BR;
    for (int t = tid; t < BS * BR; t += TTH) {
        int r = t / BS, cl = t % BS;
        Gb[(size_t)r * BR + g * BS + cl] = ((const float*)&Xs4[r / 3][cl])[r % 3];
    }
}

// Right-looking merged stage M(s):
//   near WGs (bid < nNear): rows of block s  x  cols of block s+1 -> acc, ticket
//     -> LAST ticket WG applies: F_s = G[s] @ acc_s, writes out + wf.
//   far WGs (bid >= nNear): rows < s*64  x  cols of block s+1 -> acc
//     (consumers are >=1 stage later; in-order stream guarantees arrival)
__global__ __launch_bounds__(256) void k_mstage(const float* __restrict__ E,
                                                const float* __restrict__ K,
                                                const float* __restrict__ G,
                                                float* __restrict__ acc,
                                                float* __restrict__ wf,
                                                float* __restrict__ out,
                                                int* __restrict__ cnt,
                                                int s, int nNear) {
    const size_t PL = (size_t)NE * NE;
    int i0 = s * BS;
    int jbase = (s + 1) * BS;
    int tid = threadIdx.x;
    int bid = blockIdx.x;
    int lane = tid & 63, wv = tid >> 6;
    __shared__ int win;

    if (nNear > 0 && bid >= nNear) {
        // far: 8 rows per WG, all below block s
        int rbase = (bid - nNear) * 8;
        int j = jbase + lane;
        float w0 = 0.f, w1 = 0.f, w2 = 0.f;
        if (j < NROWS) {
            w0 = wf[0 * NE + j]; w1 = wf[1 * NE + j]; w2 = wf[2 * NE + j];
        }
#pragma unroll
        for (int rr = 0; rr < 2; ++rr) {
            int row = rbase + wv + 4 * rr;
            float s0 = 0.f, s1 = 0.f, s2 = 0.f;
            if (j < NROWS) {
                const float* Kb = K + (size_t)row * NE + j;
                s0 = Kb[0 * PL] * w0 + Kb[1 * PL] * w1 + Kb[2 * PL] * w2;
                s1 = Kb[3 * PL] * w0 + Kb[4 * PL] * w1 + Kb[5 * PL] * w2;
                s2 = Kb[6 * PL] * w0 + Kb[7 * PL] * w1 + Kb[8 * PL] * w2;
            }
#pragma unroll
            for (int m = 32; m; m >>= 1) {
                s0 += __shfl_xor(s0, m);
                s1 += __shfl_xor(s1, m);
                s2 += __shfl_xor(s2, m);
            }
            if (lane == 0) {
                atomicAdd(&acc[0 * NE + row], s0);
                atomicAdd(&acc[1 * NE + row], s1);
                atomicAdd(&acc[2 * NE + row], s2);
            }
        }
        return;
    }

    if (nNear > 0) {
        // near: 4 rows per WG (one per wave), cols of block s+1
        int row = i0 + bid * 4 + wv;
        int j = jbase + lane;
        float s0 = 0.f, s1 = 0.f, s2 = 0.f;
        if (row < NROWS && j < NROWS) {
            float w0 = wf[0 * NE + j], w1 = wf[1 * NE + j], w2 = wf[2 * NE + j];
            const float* Kb = K + (size_t)row * NE + j;
            s0 = Kb[0 * PL] * w0 + Kb[1 * PL] * w1 + Kb[2 * PL] * w2;
            s1 = Kb[3 * PL] * w0 + Kb[4 * PL] * w1 + Kb[5 * PL] * w2;
            s2 = Kb[6 * PL] * w0 + Kb[7 * PL] * w1 + Kb[8 * PL] * w2;
        }
#pragma unroll
        for (int m = 32; m; m >>= 1) {
            s0 += __shfl_xor(s0, m);
            s1 += __shfl_xor(s1, m);
            s2 += __shfl_xor(s2, m);
        }
        if (lane == 0 && row < NROWS) {
            atomicAdd(&acc[0 * NE + row], s0);
            atomicAdd(&acc[1 * NE + row], s1);
            atomicAdd(&acc[2 * NE + row], s2);
        }
        // barrier drains vmcnt(0) -> this WG's RMWs are globally performed
        __syncthreads();
        if (tid == 0) {
            int ret = __hip_atomic_fetch_add(&cnt[s], 1, __ATOMIC_RELAXED,
                                             __HIP_MEMORY_SCOPE_AGENT);
            win = (ret == nNear - 1) ? 1 : 0;
        }
        __syncthreads();
        if (!win) return;
        __syncthreads();  // re-converge before the apply's shared-mem phase
    }

    // Apply: F_blk = G[s] @ acc_blk (winner WG, or sole WG for s=31)
    __shared__ float4 aL4[BR / 4];
    if (tid < BR) {
        int jj = tid / 3, p = tid % 3;
        int j = i0 + jj;
        ((float*)aL4)[tid] = (j < NROWS)
            ? __hip_atomic_load(&acc[p * NE + j], __ATOMIC_RELAXED, __HIP_MEMORY_SCOPE_AGENT)
            : 0.f;
    }
    __syncthreads();
    if (tid < BR) {
        const float4* row = (const float4*)(G + ((size_t)s * BR + tid) * BR);
        float s0 = 0.f, s1 = 0.f;
#pragma unroll
        for (int c = 0; c < BR / 4; c += 2) {
            float4 g0 = row[c], g1 = row[c + 1];
            float4 a0 = aL4[c], a1 = aL4[c + 1];
            s0 += g0.x * a0.x + g0.y * a0.y + g0.z * a0.z + g0.w * a0.w;
            s1 += g1.x * a1.x + g1.y * a1.y + g1.z * a1.z + g1.w * a1.w;
        }
        float sv = s0 + s1;
        int ii = tid / 3, x = tid % 3;
        int i = i0 + ii;
        if (i < NROWS) {
            float dy = dy_of(E);
            out[(1 + x) * NE + i] = sv > 0.f ? sv : 0.f;
            wf[x * NE + i] = dy * E[i] * sv;
        }
    }
}

extern "C" void kernel_launch(void* const* d_in, const int* in_sizes, int n_in,
                              void* d_out, int out_size, void* d_ws, size_t ws_size,
                              hipStream_t stream) {
    const float* E = (const float*)d_in[0];
    const float* R = (const float*)d_in[1];
    const float* K = (const float*)d_in[2];
    const float* S0 = (const float*)d_in[3];
    const float* SC = (const float*)d_in[4];
    float* out = (float*)d_out;
    float* wf = (float*)d_ws;
    float* acc = wf + NX * NE;
    float* G = acc + NX * NE;
    int* cnt = (int*)(G + (size_t)NBLK * BR * BR);

    k_init<<<(NE + 255) / 256, 256, 0, stream>>>(E, R, K, S0, SC, out, wf, acc, cnt);
    k_tinv<<<dim3(NBLK, 3), TTH, 0, stream>>>(E, R, K, G);

    for (int s = NBLK - 1; s >= 0; --s) {
        int nNear = (s < NBLK - 1) ? NNEAR : 0;
        int nFar = (s < NBLK - 1) ? s * 8 : 0;
        int grid = nNear + nFar;
        if (grid == 0) grid = 1;
        k_mstage<<<grid, 256, 0, stream>>>(E, K, G, acc, wf, out, cnt, s, nNear);
    }
}